// Round 1
// baseline (304.511 us; speedup 1.0000x reference)
//
#include <hip/hip_runtime.h>
#include <hip/hip_bf16.h>

typedef __bf16 bf16v8 __attribute__((ext_vector_type(8)));
typedef float f32v4 __attribute__((ext_vector_type(4)));

#define PI2F 6.28318530717958647692f

__device__ __forceinline__ int skew_i(int k) { return k + (k >> 5); }

// ---------------------------------------------------------------------------
// K1: per (b, quarter-of-frames): STFT mag partial pool, x->bf16 quarter,
//     zero expert_out slice.  grid 1024 x 128 threads.
// ---------------------------------------------------------------------------
__global__ __launch_bounds__(128) void k_stft(const float* __restrict__ x,
    float* __restrict__ pp, __hip_bfloat16* __restrict__ xb,
    float* __restrict__ eo)
{
  const int bx = blockIdx.x;
  const int b = bx >> 2, q = bx & 3;
  const int tid = threadIdx.x;
  __shared__ __align__(16) float xrow[4096];
  __shared__ float ctab[264];            // skewed cos table: addr k + (k>>5)
  __shared__ __align__(16) float vwp[132];
  __shared__ __align__(16) float vwm[132];
  __shared__ float red[2];

  { // zero expert_out: 8 MB / 1024 blocks = 8 KB each
    f32v4 z = {0.f, 0.f, 0.f, 0.f};
    f32v4* p = (f32v4*)eo + (size_t)bx * 512;
#pragma unroll
    for (int i = 0; i < 4; ++i) p[tid + i * 128] = z;
  }
  for (int k = tid; k < 256; k += 128)
    ctab[skew_i(k)] = cosf(PI2F * (1.0f / 256.0f) * (float)k);
  {
    const float4* xv = (const float4*)(x + (size_t)b * 4096);
    float4* xl = (float4*)xrow;
#pragma unroll
    for (int i = 0; i < 8; ++i) xl[tid + i * 128] = xv[tid + i * 128];
  }
  __syncthreads();
  { // convert my quarter of the row to bf16
    int c0 = q * 1024 + tid * 8;
    __align__(16) __hip_bfloat16 tmp[8];
#pragma unroll
    for (int j = 0; j < 8; ++j) tmp[j] = __float2bfloat16(xrow[c0 + j]);
    *(bf16v8*)(xb + (size_t)b * 4096 + c0) = *(bf16v8*)tmp;
  }

  const int f = tid + 1;                       // bins 1..128; bin0 via reduce
  const float cf = ctab[skew_i(f)];            // cos(2*pi*f/256)
  const float sf = ctab[skew_i((f + 192) & 255)]; // sin(2*pi*f/256)
  const int k16 = (16 * f) & 255;
  float accf = 0.f, acc0 = 0.f;
  const int t0 = q * 8;
  const int t1 = (q == 3) ? 33 : (t0 + 8);

  for (int t = t0; t < t1; ++t) {
    float v0, v1;
    {
      int p_ = t * 128 + tid;
      int xi = (p_ < 128) ? (128 - p_) : ((p_ < 4224) ? (p_ - 128) : (8318 - p_));
      v0 = xrow[xi] * (0.5f - 0.5f * ctab[skew_i(tid)]);
      p_ += 128;
      xi = (p_ < 128) ? (128 - p_) : ((p_ < 4224) ? (p_ - 128) : (8318 - p_));
      v1 = xrow[xi] * (0.5f - 0.5f * ctab[skew_i(tid + 128)]);
    }
    __syncthreads();                 // prev-frame DFT reads done
    vwp[tid] = v0 + v1;              // radix-2 fold: even bins
    vwm[tid] = v0 - v1;              // odd bins
    float s = v0 + v1;
#pragma unroll
    for (int o = 32; o; o >>= 1) s += __shfl_down(s, o);
    if ((tid & 63) == 0) red[tid >> 6] = s;
    __syncthreads();
    if (tid == 0) acc0 += fabsf(red[0] + red[1]);

    const float* vsrc = (f & 1) ? vwm : vwp;
    float re = 0.f, im = 0.f;
    int k0 = 0;
#pragma unroll 1
    for (int j = 0; j < 8; ++j) {    // resync every 16 samples (exact twiddle)
      float wr = ctab[skew_i(k0)];
      float wi = -ctab[skew_i((k0 + 192) & 255)];
      const float4* vp = (const float4*)(vsrc + j * 16);
#pragma unroll
      for (int u = 0; u < 4; ++u) {
        float4 v4 = vp[u];
        float t2;
        re += v4.x * wr; im += v4.x * wi; t2 = wr*cf + wi*sf; wi = wi*cf - wr*sf; wr = t2;
        re += v4.y * wr; im += v4.y * wi; t2 = wr*cf + wi*sf; wi = wi*cf - wr*sf; wr = t2;
        re += v4.z * wr; im += v4.z * wi; t2 = wr*cf + wi*sf; wi = wi*cf - wr*sf; wr = t2;
        re += v4.w * wr; im += v4.w * wi; t2 = wr*cf + wi*sf; wi = wi*cf - wr*sf; wr = t2;
      }
      k0 = (k0 + k16) & 255;
    }
    accf += sqrtf(re * re + im * im);
  }
  pp[(size_t)(q * 256 + b) * 132 + f] = accf;
  if (tid == 0) pp[(size_t)(q * 256 + b) * 132] = acc0;
}

// ---------------------------------------------------------------------------
// K2: gate MLP + top-2 + softmax.  grid 256 x 128 threads.
// ---------------------------------------------------------------------------
__global__ __launch_bounds__(128) void k_gate(const float* __restrict__ pp,
    const float* __restrict__ w1, const float* __restrict__ b1,
    const float* __restrict__ w2, const float* __restrict__ b2,
    int2* __restrict__ gidx, float2* __restrict__ gw)
{
  const int b = blockIdx.x, tid = threadIdx.x;
  __shared__ float pl[129];
  __shared__ float hh[128];
  __shared__ float lgt[8];
  for (int ff = tid; ff < 129; ff += 128) {
    float s = 0.f;
#pragma unroll
    for (int qq = 0; qq < 4; ++qq) s += pp[(size_t)(qq * 256 + b) * 132 + ff];
    pl[ff] = s * (1.0f / 33.0f);
  }
  __syncthreads();
  float h = b1[tid];
  for (int ff = 0; ff < 129; ++ff) h += pl[ff] * w1[ff * 128 + tid];
  hh[tid] = fmaxf(h, 0.f);
  __syncthreads();
  if (tid < 8) {
    float l = b2[tid];
    for (int j = 0; j < 128; ++j) l += hh[j] * w2[j * 8 + tid];
    lgt[tid] = l;
  }
  __syncthreads();
  if (tid == 0) {
    int i0 = 0; float v0 = lgt[0];
#pragma unroll
    for (int i = 1; i < 8; ++i) if (lgt[i] > v0) { v0 = lgt[i]; i0 = i; }
    int i1 = -1; float v1 = -3.4e38f;
#pragma unroll
    for (int i = 0; i < 8; ++i) { if (i == i0) continue; if (lgt[i] > v1) { v1 = lgt[i]; i1 = i; } }
    float e1 = expf(v1 - v0);
    float wA = 1.0f / (1.0f + e1);
    gidx[b] = make_int2(i0, i1);
    gw[b] = make_float2(wA, e1 * wA);
  }
}

// ---------------------------------------------------------------------------
// K3: expert GEMM, bf16 MFMA. BM=256(all rows) BN=64 Ksplit=4, BK=32.
//     grid 512 x 256 threads. Weights read from HBM exactly once.
// ---------------------------------------------------------------------------
__global__ __launch_bounds__(256) void k_gemm(const __hip_bfloat16* __restrict__ xb,
    const float* __restrict__ W, float* __restrict__ eo)
{
  const int bx = blockIdx.x;
  const int ks = bx & 3, nt = (bx >> 2) & 15, e = bx >> 6;
  const int n0 = nt * 64;
  const int kbase = ks * 1024;
  const int tid = threadIdx.x;
  const int w = tid >> 6, l = tid & 63;
  const int lr = l & 15, lgp = l >> 4;
  __shared__ __hip_bfloat16 XL[256][40];   // 32 cols + pad8 (80 B stride)
  __shared__ __hip_bfloat16 WL[64][40];    // transposed [n][k], 32 + pad8
  f32v4 acc[4][4];
  f32v4 z = {0.f, 0.f, 0.f, 0.f};
#pragma unroll
  for (int m = 0; m < 4; ++m)
#pragma unroll
    for (int nb = 0; nb < 4; ++nb) acc[m][nb] = z;
  const float* Wp = W + ((size_t)e << 22) + n0;
  const int sx_seg = tid & 3, sx_row = tid >> 2;
  const int sw_n = tid & 63, sw_k4 = tid >> 6;
  for (int kc = 0; kc < 32; ++kc) {
    const int kb = kbase + kc * 32;
#pragma unroll
    for (int p = 0; p < 4; ++p) {
      int row = p * 64 + sx_row;
      *(bf16v8*)(&XL[row][sx_seg * 8]) =
          *(const bf16v8*)(xb + (size_t)row * 4096 + kb + sx_seg * 8);
    }
#pragma unroll
    for (int p = 0; p < 8; ++p) {
      int kk = p * 4 + sw_k4;
      WL[sw_n][kk] = __float2bfloat16(Wp[(size_t)(kb + kk) * 1024 + sw_n]);
    }
    __syncthreads();
    bf16v8 af[4], bfr[4];
#pragma unroll
    for (int m = 0; m < 4; ++m)
      af[m] = *(const bf16v8*)(&XL[w * 64 + m * 16 + lr][lgp * 8]);
#pragma unroll
    for (int nb = 0; nb < 4; ++nb)
      bfr[nb] = *(const bf16v8*)(&WL[nb * 16 + lr][lgp * 8]);
#pragma unroll
    for (int m = 0; m < 4; ++m)
#pragma unroll
      for (int nb = 0; nb < 4; ++nb)
        acc[m][nb] = __builtin_amdgcn_mfma_f32_16x16x32_bf16(af[m], bfr[nb], acc[m][nb], 0, 0, 0);
    __syncthreads();
  }
#pragma unroll
  for (int m = 0; m < 4; ++m)
#pragma unroll
    for (int nb = 0; nb < 4; ++nb)
#pragma unroll
      for (int r = 0; r < 4; ++r) {
        int row = w * 64 + m * 16 + lgp * 4 + r;
        int col = n0 + nb * 16 + lr;
        atomicAdd(eo + ((size_t)e * 256 + row) * 1024 + col, acc[m][nb][r]);
      }
}

// ---------------------------------------------------------------------------
// K4: weighted gather + bias.  grid 256 x 256 threads.
// ---------------------------------------------------------------------------
__global__ __launch_bounds__(256) void k_gather(const float* __restrict__ eo,
    const float* __restrict__ eb, const int2* __restrict__ gidx,
    const float2* __restrict__ gw, float* __restrict__ out)
{
  const int b = blockIdx.x, tid = threadIdx.x;
  const int2 ii = gidx[b];
  const float2 wwv = gw[b];
  const float4* r0 = (const float4*)(eo + ((size_t)ii.x * 256 + b) * 1024);
  const float4* r1 = (const float4*)(eo + ((size_t)ii.y * 256 + b) * 1024);
  const float4* b0 = (const float4*)(eb + (size_t)ii.x * 1024);
  const float4* b1p = (const float4*)(eb + (size_t)ii.y * 1024);
  float4* op = (float4*)(out + (size_t)b * 1024);
  float4 a = r0[tid], c = r1[tid], ba = b0[tid], bc = b1p[tid];
  float4 o;
  o.x = wwv.x * (a.x + ba.x) + wwv.y * (c.x + bc.x);
  o.y = wwv.x * (a.y + ba.y) + wwv.y * (c.y + bc.y);
  o.z = wwv.x * (a.z + ba.z) + wwv.y * (c.z + bc.z);
  o.w = wwv.x * (a.w + ba.w) + wwv.y * (c.w + bc.w);
  op[tid] = o;
}

extern "C" void kernel_launch(void* const* d_in, const int* in_sizes, int n_in,
                              void* d_out, int out_size, void* d_ws, size_t ws_size,
                              hipStream_t stream) {
  const float* x  = (const float*)d_in[0];
  const float* w1 = (const float*)d_in[1];
  const float* b1 = (const float*)d_in[2];
  const float* w2 = (const float*)d_in[3];
  const float* b2 = (const float*)d_in[4];
  const float* W  = (const float*)d_in[5];
  const float* eb = (const float*)d_in[6];
  float* out = (float*)d_out;
  char* ws = (char*)d_ws;

  float* eo            = (float*)ws;                                  // 8 MB
  __hip_bfloat16* xb   = (__hip_bfloat16*)(ws + 8388608);             // 2 MB
  float* pp            = (float*)(ws + 8388608 + 2097152);            // 528 KB+
  int2* gidx           = (int2*)(ws + 8388608 + 2097152 + 540672);
  float2* gw           = (float2*)(ws + 8388608 + 2097152 + 540672 + 2048);

  hipLaunchKernelGGL(k_stft,   dim3(1024), dim3(128), 0, stream, x, pp, xb, eo);
  hipLaunchKernelGGL(k_gate,   dim3(256),  dim3(128), 0, stream, pp, w1, b1, w2, b2, gidx, gw);
  hipLaunchKernelGGL(k_gemm,   dim3(512),  dim3(256), 0, stream, xb, W, eo);
  hipLaunchKernelGGL(k_gather, dim3(256),  dim3(256), 0, stream, eo, eb, gidx, gw, out);
}

// Round 4
// 273.134 us; speedup vs baseline: 1.1149x; 1.1149x over previous
//
#include <hip/hip_runtime.h>
#include <hip/hip_bf16.h>

typedef __bf16 bf16v8 __attribute__((ext_vector_type(8)));
typedef float f32v4 __attribute__((ext_vector_type(4)));
typedef unsigned int u32;

#define PI2F 6.28318530717958647692f
__device__ __forceinline__ int skew_i(int k) { return k + (k >> 5); }

#define GLL16(g, s) __builtin_amdgcn_global_load_lds( \
    (const __attribute__((address_space(1))) u32*)(g), \
    (__attribute__((address_space(3))) u32*)(s), 16, 0, 0)

// ---------------------------------------------------------------------------
// K1: STFT mag partial pool (4-frame-batched DFT), x->bf16, zero ridx/rw/cnt.
//     grid 1024 x 128.
// ---------------------------------------------------------------------------
__global__ __launch_bounds__(128) void k_stft(const float* __restrict__ x,
    float* __restrict__ pp, __hip_bfloat16* __restrict__ xb,
    int* __restrict__ ridx /* ridx(8KB)+rw(8KB) contiguous */,
    int* __restrict__ cnt)
{
  const int bx = blockIdx.x, b = bx >> 2, q = bx & 3, tid = threadIdx.x;
  __shared__ __align__(16) float xrow[4096];
  __shared__ float ctab[264];
  __shared__ __align__(16) float vwp4[128][4];   // [k][frame]
  __shared__ __align__(16) float vwm4[128][4];
  __shared__ __align__(16) float red[2][4];

  if (bx < 16)  // zero ridx+rw (16KB contiguous)
    ((float2*)((char*)ridx + (size_t)bx * 1024))[tid] = make_float2(0.f, 0.f);
  if (bx == 16 && tid < 8) cnt[tid] = 0;

  for (int k = tid; k < 256; k += 128)
    ctab[skew_i(k)] = cosf(PI2F * (1.0f / 256.0f) * (float)k);
  {
    const float4* xv = (const float4*)(x + (size_t)b * 4096);
    float4* xl = (float4*)xrow;
#pragma unroll
    for (int i = 0; i < 8; ++i) xl[tid + i * 128] = xv[tid + i * 128];
  }
  __syncthreads();
  {  // convert my quarter of the row to bf16
    int c0 = q * 1024 + tid * 8;
    __align__(16) __hip_bfloat16 tmp[8];
#pragma unroll
    for (int j = 0; j < 8; ++j) tmp[j] = __float2bfloat16(xrow[c0 + j]);
    *(bf16v8*)(xb + (size_t)b * 4096 + c0) = *(bf16v8*)tmp;
  }

  const int f = tid + 1;                            // bins 1..128
  const float cf = ctab[skew_i(f)];                 // cos(2pi f/256)
  const float sf = ctab[skew_i((f + 192) & 255)];   // sin(2pi f/256)
  const int k16 = (16 * f) & 255;
  float accf = 0.f, acc0 = 0.f;
  const int nGroups = (q == 3) ? 3 : 2;

  for (int g = 0; g < nGroups; ++g) {
    float vp_[4], vm_[4], sm_[4];
#pragma unroll
    for (int fr = 0; fr < 4; ++fr) {
      int t = q * 8 + g * 4 + fr;
      float v0 = 0.f, v1 = 0.f;
      if (t < 33) {
        int p_ = t * 128 + tid;
        int xi = (p_ < 128) ? (128 - p_) : ((p_ < 4224) ? (p_ - 128) : (8318 - p_));
        v0 = xrow[xi] * (0.5f - 0.5f * ctab[skew_i(tid)]);
        p_ += 128;
        xi = (p_ < 128) ? (128 - p_) : ((p_ < 4224) ? (p_ - 128) : (8318 - p_));
        v1 = xrow[xi] * (0.5f - 0.5f * ctab[skew_i(tid + 128)]);
      }
      vp_[fr] = v0 + v1; vm_[fr] = v0 - v1; sm_[fr] = v0 + v1;
    }
#pragma unroll
    for (int o = 32; o; o >>= 1) {
#pragma unroll
      for (int fr = 0; fr < 4; ++fr) sm_[fr] += __shfl_down(sm_[fr], o);
    }
    __syncthreads();                       // prior group's DFT reads done
    *(float4*)&vwp4[tid][0] = make_float4(vp_[0], vp_[1], vp_[2], vp_[3]);
    *(float4*)&vwm4[tid][0] = make_float4(vm_[0], vm_[1], vm_[2], vm_[3]);
    if ((tid & 63) == 0)
      *(float4*)&red[tid >> 6][0] = make_float4(sm_[0], sm_[1], sm_[2], sm_[3]);
    __syncthreads();
    if (tid == 0) {
#pragma unroll
      for (int fr = 0; fr < 4; ++fr) acc0 += fabsf(red[0][fr] + red[1][fr]);
    }
    const float4* vsrc = (const float4*)((f & 1) ? &vwm4[0][0] : &vwp4[0][0]);
    float re0 = 0, im0 = 0, re1 = 0, im1 = 0, re2 = 0, im2 = 0, re3 = 0, im3 = 0;
    int k0 = 0;
#pragma unroll 1
    for (int j = 0; j < 8; ++j) {          // exact twiddle resync every 16
      float wr = ctab[skew_i(k0)];
      float wi = -ctab[skew_i((k0 + 192) & 255)];
#pragma unroll
      for (int u = 0; u < 16; ++u) {
        float4 a = vsrc[j * 16 + u];       // broadcast read: all 4 frames at k
        re0 += a.x * wr; im0 += a.x * wi;
        re1 += a.y * wr; im1 += a.y * wi;
        re2 += a.z * wr; im2 += a.z * wi;
        re3 += a.w * wr; im3 += a.w * wi;
        float t2 = wr * cf + wi * sf; wi = wi * cf - wr * sf; wr = t2;
      }
      k0 = (k0 + k16) & 255;
    }
    accf += sqrtf(re0 * re0 + im0 * im0) + sqrtf(re1 * re1 + im1 * im1)
          + sqrtf(re2 * re2 + im2 * im2) + sqrtf(re3 * re3 + im3 * im3);
  }
  pp[(size_t)(q * 256 + b) * 132 + f] = accf;
  if (tid == 0) pp[(size_t)(q * 256 + b) * 132] = acc0;
}

// ---------------------------------------------------------------------------
// K2: gate MLP + top-2 + softmax + expert-row compaction + out := w*bias.
//     grid 256 x 128.
// ---------------------------------------------------------------------------
__global__ __launch_bounds__(128) void k_gate(const float* __restrict__ pp,
    const float* __restrict__ w1, const float* __restrict__ b1,
    const float* __restrict__ w2, const float* __restrict__ b2,
    const float* __restrict__ eb,
    int* __restrict__ ridx, float* __restrict__ rw, int* __restrict__ cnt,
    float* __restrict__ out)
{
  const int b = blockIdx.x, tid = threadIdx.x;
  __shared__ float pl[129];
  __shared__ float hh[128];
  __shared__ float lgt[8];
  __shared__ int sIdx[2];
  __shared__ float sW[2];
  for (int ff = tid; ff < 129; ff += 128) {
    float s = 0.f;
#pragma unroll
    for (int qq = 0; qq < 4; ++qq) s += pp[(size_t)(qq * 256 + b) * 132 + ff];
    pl[ff] = s * (1.0f / 33.0f);
  }
  __syncthreads();
  float h = b1[tid];
  for (int ff = 0; ff < 129; ++ff) h += pl[ff] * w1[ff * 128 + tid];
  hh[tid] = fmaxf(h, 0.f);
  __syncthreads();
  if (tid < 8) {
    float l = b2[tid];
    for (int j = 0; j < 128; ++j) l += hh[j] * w2[j * 8 + tid];
    lgt[tid] = l;
  }
  __syncthreads();
  if (tid == 0) {
    int i0 = 0; float v0 = lgt[0];
#pragma unroll
    for (int i = 1; i < 8; ++i) if (lgt[i] > v0) { v0 = lgt[i]; i0 = i; }
    int i1 = -1; float v1 = -3.4e38f;
#pragma unroll
    for (int i = 0; i < 8; ++i) { if (i == i0) continue; if (lgt[i] > v1) { v1 = lgt[i]; i1 = i; } }
    float e1 = expf(v1 - v0);
    float wA = 1.0f / (1.0f + e1);
    float wB = e1 * wA;
    sIdx[0] = i0; sIdx[1] = i1; sW[0] = wA; sW[1] = wB;
    int s0 = atomicAdd(&cnt[i0], 1); ridx[i0 * 256 + s0] = b; rw[i0 * 256 + s0] = wA;
    int s1 = atomicAdd(&cnt[i1], 1); ridx[i1 * 256 + s1] = b; rw[i1 * 256 + s1] = wB;
  }
  __syncthreads();
  const float4* e0 = (const float4*)(eb + (size_t)sIdx[0] * 1024);
  const float4* e1p = (const float4*)(eb + (size_t)sIdx[1] * 1024);
  const float wA = sW[0], wB = sW[1];
  float4* op = (float4*)(out + (size_t)b * 1024);
#pragma unroll
  for (int i = 0; i < 2; ++i) {
    float4 a = e0[tid + i * 128], c = e1p[tid + i * 128];
    float4 o;
    o.x = wA * a.x + wB * c.x; o.y = wA * a.y + wB * c.y;
    o.z = wA * a.z + wB * c.z; o.w = wA * a.w + wB * c.w;
    op[tid + i * 128] = o;
  }
}

// ---------------------------------------------------------------------------
// K3: gated expert GEMM. BM=256 slots (live rows only), BN=32, BK=64, ks=4.
//     grid 1024 x 256. Fragment-ordered LDS (conflict-free); X via
//     global_load_lds with pre-swizzled per-lane sources; atomicAdd into out.
// ---------------------------------------------------------------------------
__global__ __launch_bounds__(256, 4) void k_gemm(const __hip_bfloat16* __restrict__ xb,
    const float* __restrict__ W, const int* __restrict__ ridx,
    const float* __restrict__ rw, const int* __restrict__ cnt,
    float* __restrict__ out)
{
  const int bx = blockIdx.x;
  const int ks = bx & 3, nt = (bx >> 2) & 31, e = bx >> 7;
  const int cntE = cnt[e];
  if (cntE == 0) return;
  const int tid = threadIdx.x, w = tid >> 6, l = tid & 63;
  const int lr = l & 15, lgp = l >> 4;
  __shared__ __align__(16) __hip_bfloat16 XLf[16384];  // 32KB fragment-ordered
  __shared__ __align__(16) __hip_bfloat16 WLf[2048];   // 4KB fragment-ordered

  // per-lane global byte offsets for the 8 X chunks this thread feeds
  u32 xoff[8];
#pragma unroll
  for (int i = 0; i < 8; ++i) {
    int mts = (w * 8 + i) >> 1;        // chunk's m-tile
    int ksd = i & 1;
    int row = mts * 16 + lr;
    int bRow = ridx[e * 256 + row];    // 0 for padded slots (zero-filled)
    xoff[i] = (u32)bRow * 8192u + (u32)ks * 2048u + (u32)ksd * 64u + (u32)lgp * 16u;
  }
  const char* xbB = (const char*)xb;
  char* XLb = (char*)XLf;
  const int k2 = tid >> 3, nseg = tid & 7;
  const float* Wp = W + ((size_t)e << 22) + ((size_t)ks << 20) + nt * 32 + nseg * 4;

  f32v4 acc[4][2];
  const f32v4 z = {0.f, 0.f, 0.f, 0.f};
#pragma unroll
  for (int m = 0; m < 4; ++m) { acc[m][0] = z; acc[m][1] = z; }

  for (int kc = 0; kc < 16; ++kc) {
    // W: two float4 rows (k pair 2k2, 2k2+1), coalesced 128B per 8 lanes
    float4 Wa = *(const float4*)(Wp + (size_t)(kc * 64 + 2 * k2) * 1024);
    float4 Wb = *(const float4*)(Wp + (size_t)(kc * 64 + 2 * k2) * 1024 + 1024);
    // X: async global->LDS, skip dead m-tiles
    const u32 kcb = (u32)kc * 128u;
#pragma unroll
    for (int i = 0; i < 8; ++i) {
      int mts = (w * 8 + i) >> 1;
      if (mts * 16 < cntE)
        GLL16(xbB + xoff[i] + kcb, XLb + ((w * 8 + i) << 10));
    }
    // W: convert + packed LDS writes into fragment layout
    {
      int kk = 2 * k2;
      int ksd = kk >> 5, lgpd = (kk >> 3) & 3, wsl = k2 & 3;
      float a_[4] = {Wa.x, Wa.y, Wa.z, Wa.w};
      float b_[4] = {Wb.x, Wb.y, Wb.z, Wb.w};
#pragma unroll
      for (int i = 0; i < 4; ++i) {
        int n = nseg * 4 + i;
        int ntile = n >> 4, lrd = n & 15;
        union { __hip_bfloat16 h[2]; u32 u; } pk;
        pk.h[0] = __float2bfloat16(a_[i]);
        pk.h[1] = __float2bfloat16(b_[i]);
        ((u32*)WLf)[((((ntile * 2 + ksd) << 6) + (lgpd << 4) + lrd) << 2) + wsl] = pk.u;
      }
    }
    __syncthreads();
    bf16v8 bfr[2][2];
#pragma unroll
    for (int nb = 0; nb < 2; ++nb)
#pragma unroll
      for (int ksd = 0; ksd < 2; ++ksd)
        bfr[nb][ksd] = *(const bf16v8*)((const char*)WLf + (((((nb * 2 + ksd) << 6) + l)) << 4));
#pragma unroll
    for (int m = 0; m < 4; ++m) {
      int mt = m * 4 + w;                 // wave-interleaved m-tiles (balance)
      if (mt * 16 < cntE) {
#pragma unroll
        for (int ksd = 0; ksd < 2; ++ksd) {
          bf16v8 af = *(const bf16v8*)(XLb + (((((mt * 2 + ksd) << 6) + l)) << 4));
          acc[m][0] = __builtin_amdgcn_mfma_f32_16x16x32_bf16(af, bfr[0][ksd], acc[m][0], 0, 0, 0);
          acc[m][1] = __builtin_amdgcn_mfma_f32_16x16x32_bf16(af, bfr[1][ksd], acc[m][1], 0, 0, 0);
        }
      }
    }
    __syncthreads();
  }
  // epilogue: scale by gate weight, atomicAdd into out (bias pre-added by k_gate)
#pragma unroll
  for (int m = 0; m < 4; ++m) {
    int mt = m * 4 + w;
    if (mt * 16 >= cntE) continue;
#pragma unroll
    for (int r = 0; r < 4; ++r) {
      int row = mt * 16 + lgp * 4 + r;
      float wgt = rw[e * 256 + row];
      if (wgt != 0.f) {
        int bRow = ridx[e * 256 + row];
        float* o = out + (size_t)bRow * 1024 + nt * 32 + lr;
        atomicAdd(o, acc[m][0][r] * wgt);
        atomicAdd(o + 16, acc[m][1][r] * wgt);
      }
    }
  }
}

extern "C" void kernel_launch(void* const* d_in, const int* in_sizes, int n_in,
                              void* d_out, int out_size, void* d_ws, size_t ws_size,
                              hipStream_t stream) {
  const float* x  = (const float*)d_in[0];
  const float* w1 = (const float*)d_in[1];
  const float* b1 = (const float*)d_in[2];
  const float* w2 = (const float*)d_in[3];
  const float* b2 = (const float*)d_in[4];
  const float* W  = (const float*)d_in[5];
  const float* eb = (const float*)d_in[6];
  float* out = (float*)d_out;
  char* ws = (char*)d_ws;

  __hip_bfloat16* xb = (__hip_bfloat16*)ws;                      // 2 MB
  float* pp  = (float*)(ws + 2097152);                           // 540672 B
  int*   ridx = (int*)(ws + 2097152 + 540672);                   // 8 KB
  float* rw   = (float*)(ws + 2097152 + 540672 + 8192);          // 8 KB (contiguous after ridx)
  int*   cnt  = (int*)(ws + 2097152 + 540672 + 16384);           // 32 B

  hipLaunchKernelGGL(k_stft, dim3(1024), dim3(128), 0, stream, x, pp, xb, ridx, cnt);
  hipLaunchKernelGGL(k_gate, dim3(256), dim3(128), 0, stream, pp, w1, b1, w2, b2, eb, ridx, rw, cnt, out);
  hipLaunchKernelGGL(k_gemm, dim3(1024), dim3(256), 0, stream, xb, W, ridx, rw, cnt, out);
}